// Round 2
// baseline (524.915 us; speedup 1.0000x reference)
//
#include <hip/hip_runtime.h>
#include <cstdint>

#define HH 72
#define NR 16          // rows per block: 2 independent groups of 8
#define NTH 576
#define NBLK 128
#define TT 512

typedef __attribute__((ext_vector_type(8))) _Float16 half8;
typedef __attribute__((ext_vector_type(4))) float f32x4;

#if __has_builtin(__builtin_amdgcn_exp2f)
#define EXP2(x) __builtin_amdgcn_exp2f(x)
#else
#define EXP2(x) exp2f(x)
#endif
#if __has_builtin(__builtin_amdgcn_rcpf)
#define RCP(x) __builtin_amdgcn_rcpf(x)
#else
#define RCP(x) (1.0f/(x))
#endif

__device__ __forceinline__ float fsig(float x) {
  float e = EXP2(x * -1.442695040888963f);
  return RCP(1.0f + e);
}
__device__ __forceinline__ float ftanh(float x) {
  float e = EXP2(x * -2.885390081777927f);
  return fmaf(2.0f, RCP(1.0f + e), -1.0f);
}

// fp32 -> fp16 bits (RNE via v_cvt_f16_f32)
__device__ __forceinline__ unsigned short f2h(float v) {
  union { _Float16 h; unsigned short u; } cv;
  cv.h = (_Float16)v;
  return cv.u;
}

// fragment ushort index for contraction-dim k, batch col m (0..7).
// Layout [kt*4+q][m=8][8]: 8 contiguous fp16 -> one ds_read_b128 per (group,m).
__device__ __forceinline__ int bidx(int k, int m) {
  return ((k >> 5)*4 + ((k >> 3) & 3))*64 + m*8 + (k & 7);
}

__device__ __forceinline__ float cellUpd(float ig, float fg, float gg, float og, float& c) {
  c = fmaf(fsig(fg), c, fsig(ig)*ftanh(gg));
  return fsig(og)*ftanh(c);
}

// accumulate 8 rows: A[j] += W_ * P_[j]
#define FMA8(A, W_, P_) { \
  const float4 _fa = *(const float4*)(P_); \
  const float4 _fb = *(const float4*)((P_) + 4); \
  A[0] = fmaf((W_), _fa.x, A[0]); A[1] = fmaf((W_), _fa.y, A[1]); \
  A[2] = fmaf((W_), _fa.z, A[2]); A[3] = fmaf((W_), _fa.w, A[3]); \
  A[4] = fmaf((W_), _fb.x, A[4]); A[5] = fmaf((W_), _fb.y, A[5]); \
  A[6] = fmaf((W_), _fb.z, A[6]); A[7] = fmaf((W_), _fb.w, A[7]); }

// counting sort of rows by h_lens (ascending) -> blocks get similar-length rows
__global__ void cfm_sort(const int* __restrict__ h_lens, int* __restrict__ perm) {
  __shared__ int hist[257];
  __shared__ int offs[257];
  const int t = threadIdx.x; // 256
  for (int i = t; i < 257; i += 256) hist[i] = 0;
  __syncthreads();
  for (int i = t; i < 2048; i += 256) {
    int bkt = min(max(h_lens[i] - 256, 0), 256);
    atomicAdd(&hist[bkt], 1);
  }
  __syncthreads();
  if (t == 0) { int s = 0; for (int i = 0; i < 257; ++i) { offs[i] = s; s += hist[i]; } }
  __syncthreads();
  for (int i = t; i < 2048; i += 256) {
    int bkt = min(max(h_lens[i] - 256, 0), 256);
    int pos = atomicAdd(&offs[bkt], 1);
    perm[pos] = i;
  }
}

// 16 rows/block as TWO independent groups of 8 (X=rows 0-7, Y=rows 8-15).
// 9 waves x 2 tiles; every lane owns one (unit,batch) cell per group.
// The two groups' chains interleave -> latency of one hides under issue of the other.
__global__ __launch_bounds__(NTH, 2)
void cfm_main(const float* __restrict__ x, const float* __restrict__ rnn,
              const float* __restrict__ deltas, const int* __restrict__ h_lens,
              const float* __restrict__ W_ih, const float* __restrict__ W_hh,
              const float* __restrict__ b_ih, const float* __restrict__ b_hh,
              const float* __restrict__ eW1, const float* __restrict__ eb1,
              const float* __restrict__ eW2, const float* __restrict__ eb2,
              const float* __restrict__ eW3, const float* __restrict__ eb3,
              const float* __restrict__ dW1, const float* __restrict__ db1,
              const float* __restrict__ dW2, const float* __restrict__ db2,
              const float* __restrict__ dW3, const float* __restrict__ db3,
              const int* __restrict__ perm, float* __restrict__ out)
{
  __shared__ __align__(16) unsigned short hF[2][2][768]; // [group][par][frag] fp16 B-fragments
  __shared__ __align__(16) float gS[4608];               // enc z1S / dec d2S  [n][16]
  __shared__ __align__(16) float rnnS[16*292];           // rnn chunk [16][292]; enc z2S / dec d1S [n][16]
  __shared__ __align__(16) float snapP[NR][HH];
  __shared__ __align__(16) float snapC[NR][HH];
  __shared__ __align__(16) float hS[HH*16];              // decoder dec_in [u][r]
  __shared__ __align__(16) float xS[8*16];               // [k][r]
  __shared__ int brS[NR];
  __shared__ int idxS[NR];
  __shared__ float dS[NR];

  const int t  = threadIdx.x;
  const int bb = blockIdx.x;

  for (int i = t; i < 1536; i += NTH) ((unsigned*)hF)[i] = 0;  // zero both groups+bufs (pads!)

  if (t < NR) {
    int row = perm ? perm[bb*NR + t] : (bb*NR + t);
    brS[t]  = row;
    idxS[t] = h_lens[row] - 1;   // in [255, 511]
  }
  __syncthreads();

  int maxIdx = idxS[0];
  #pragma unroll
  for (int r = 1; r < NR; ++r) maxIdx = max(maxIdx, idxS[r]);

  const int lane = t & 63;
  const int wv   = t >> 6;                 // 0..8, tiles {2wv, 2wv+1}
  const int col  = lane & 15;
  const int q_a  = lane >> 4;
  const int cL   = col & 7;                // batch col within group
  const int gHi  = col >> 3;               // which of my wave's 2 tiles
  const int uA   = 4*(2*wv + gHi) + q_a;   // unit owned
  const int cidxX   = idxS[cL];
  const int cidxXm1 = cidxX - 1;
  const int cidxY   = idxS[8 + cL];
  const int cidxYm1 = cidxY - 1;
  const int ibA  = bidx(uA, cL);
  const int bOff0 = (0*4 + q_a)*64 + cL*8; // broadcast read: col&7
  const int bOff1 = (1*4 + q_a)*64 + cL*8;
  const int bOff2 = (2*4 + q_a)*64 + cL*8;
  float cstX = 0.f, cstY = 0.f;
  float hvPX = 0.f, hvCX = 0.f, hvPY = 0.f, hvCY = 0.f;

  // prefetch rnn chunk 0 into regs (2 float4/thread: 1152 float4 = 16 rows * 288 floats)
  const int pfR = t / 72;                  // 0..7
  const int pfP = t - pfR*72;              // 0..71
  const float4* rnnRowA = (const float4*)(rnn + (size_t)brS[pfR]*4608) + pfP;
  const float4* rnnRowB = (const float4*)(rnn + (size_t)brS[pfR + 8]*4608) + pfP;
  float4 pfA = rnnRowA[0];
  float4 pfB = rnnRowB[0];

  // xt staging lanes: 144 values/step (16 rows x 9 k)
  const bool doXt = (t < 144);
  int xtDst = 0, xtSrc = 0, xtG = 0;
  if (doXt) {
    int rX = t / 9, kX = t - rX*9;         // rX 0..15
    xtG   = rX >> 3;
    xtDst = bidx(72 + kX, rX & 7);
    xtSrc = rX*292 + kX;                   // padded row stride 292
  }

  // ---------------- encoder: 8 -> 256 -> 256 -> 64 (16 rows) ----------------
  if (t < 128) { int r = t >> 3, k = t & 7; xS[k*16 + r] = x[brS[r]*8 + k]; }
  __syncthreads();

  float* z1S = gS;   // [n][16]
  if (t < 512) {
    int n = t >> 1, rh = (t & 1)*8;
    float acc[8];
    float b = eb1[n];
    #pragma unroll
    for (int j = 0; j < 8; ++j) acc[j] = b;
    #pragma unroll
    for (int k = 0; k < 8; ++k) { float w = eW1[n*8 + k]; FMA8(acc, w, &xS[k*16 + rh]); }
    #pragma unroll
    for (int j = 0; j < 8; ++j) z1S[n*16 + rh + j] = ftanh(acc[j]);
  }
  __syncthreads();
  float* z2S = rnnS; // [n][16]
  if (t < 512) {
    int n = t >> 1, rh = (t & 1)*8;
    float acc[8];
    float b = eb2[n];
    #pragma unroll
    for (int j = 0; j < 8; ++j) acc[j] = b;
    const float4* w4 = (const float4*)(eW2 + n*256);
    #pragma unroll 2
    for (int k4 = 0; k4 < 64; ++k4) {
      float4 w = w4[k4];
      FMA8(acc, w.x, &z1S[(4*k4+0)*16 + rh]);
      FMA8(acc, w.y, &z1S[(4*k4+1)*16 + rh]);
      FMA8(acc, w.z, &z1S[(4*k4+2)*16 + rh]);
      FMA8(acc, w.w, &z1S[(4*k4+3)*16 + rh]);
    }
    #pragma unroll
    for (int j = 0; j < 8; ++j) z2S[n*16 + rh + j] = ftanh(acc[j]);
  }
  __syncthreads();
  if (t < 128) {                       // h0 (linear) -> fragment k = 8+o, buffer 0
    int o = t >> 1, rh = (t & 1)*8;    // o 0..63, rows rh..rh+7 = group rh>>3
    float acc[8];
    float b = eb3[o];
    #pragma unroll
    for (int j = 0; j < 8; ++j) acc[j] = b;
    const float4* w4 = (const float4*)(eW3 + o*256);
    #pragma unroll 2
    for (int k4 = 0; k4 < 64; ++k4) {
      float4 w = w4[k4];
      FMA8(acc, w.x, &z2S[(4*k4+0)*16 + rh]);
      FMA8(acc, w.y, &z2S[(4*k4+1)*16 + rh]);
      FMA8(acc, w.z, &z2S[(4*k4+2)*16 + rh]);
      FMA8(acc, w.w, &z2S[(4*k4+3)*16 + rh]);
    }
    int grp = rh >> 3;
    #pragma unroll
    for (int j = 0; j < 8; ++j) hF[grp][0][bidx(8 + o, j)] = f2h(acc[j]);
  } else if (t < 256) {                // x part -> k = 0..7, buffer 0
    int tt2 = t - 128; int r = tt2 >> 3, k = tt2 & 7;
    hF[r >> 3][0][bidx(k, r & 7)] = f2h(xS[k*16 + r]);
  }

  // ---------------- weights as fp16 A-fragments (gate-permuted rows) ----------------
  // n' = 4*unit + gate ; src row = gate*72 + unit. A[row=n'][k], k = kt*32+q_a*8+j.
  // Shared between the two batch groups.
  half8 Af[2][3];
  f32x4 biasq[2];
  #pragma unroll
  for (int i = 0; i < 2; ++i) {
    int u = 4*(2*wv + i) + q_a;
    biasq[i].x = b_ih[u]       + b_hh[u];
    biasq[i].y = b_ih[72 + u]  + b_hh[72 + u];
    biasq[i].z = b_ih[144 + u] + b_hh[144 + u];
    biasq[i].w = b_ih[216 + u] + b_hh[216 + u];
    int nprime = (2*wv + i)*16 + col;
    int srcrow = (nprime & 3)*72 + (nprime >> 2);
    #pragma unroll
    for (int kt = 0; kt < 3; ++kt) {
      union { unsigned short u16[8]; half8 h; } cw;
      #pragma unroll
      for (int j = 0; j < 8; ++j) {
        int k = kt*32 + q_a*8 + j;
        float v = 0.f;
        if (k < 72)      v = W_hh[srcrow*HH + k];
        else if (k < 81) v = W_ih[srcrow*9 + (k - 72)];
        cw.u16[j] = f2h(v);
      }
      Af[i][kt] = cw.h;
    }
  }

  // ---------------- LSTM over time: one barrier per step, 2 groups interleaved ----
#define MFMA16(A, B, C) __builtin_amdgcn_mfma_f32_16x16x32_f16(A, B, C, 0, 0, 0)
#define STEP(PAR) { \
    const unsigned short* hbX = &hF[0][PAR][0]; \
    const unsigned short* hbY = &hF[1][PAR][0]; \
    unsigned short* hnX = &hF[0][(PAR) ^ 1][0]; \
    unsigned short* hnY = &hF[1][(PAR) ^ 1][0]; \
    half8 bx0 = *(const half8*)(hbX + bOff0); \
    half8 bx1 = *(const half8*)(hbX + bOff1); \
    half8 bx2 = *(const half8*)(hbX + bOff2); \
    half8 by0 = *(const half8*)(hbY + bOff0); \
    half8 by1 = *(const half8*)(hbY + bOff1); \
    half8 by2 = *(const half8*)(hbY + bOff2); \
    f32x4 ax0 = MFMA16(Af[0][0], bx0, biasq[0]); \
    f32x4 ax1 = MFMA16(Af[1][0], bx0, biasq[1]); \
    f32x4 ay0 = MFMA16(Af[0][0], by0, biasq[0]); \
    f32x4 ay1 = MFMA16(Af[1][0], by0, biasq[1]); \
    ax0 = MFMA16(Af[0][1], bx1, ax0);  ax1 = MFMA16(Af[1][1], bx1, ax1); \
    ay0 = MFMA16(Af[0][1], by1, ay0);  ay1 = MFMA16(Af[1][1], by1, ay1); \
    ax0 = MFMA16(Af[0][2], bx2, ax0);  ax1 = MFMA16(Af[1][2], bx2, ax1); \
    ay0 = MFMA16(Af[0][2], by2, ay0);  ay1 = MFMA16(Af[1][2], by2, ay1); \
    float igX = gHi ? ax1.x : ax0.x, fgX = gHi ? ax1.y : ax0.y; \
    float ggX = gHi ? ax1.z : ax0.z, ogX = gHi ? ax1.w : ax0.w; \
    float igY = gHi ? ay1.x : ay0.x, fgY = gHi ? ay1.y : ay0.y; \
    float ggY = gHi ? ay1.z : ay0.z, ogY = gHi ? ay1.w : ay0.w; \
    float hvX = cellUpd(igX, fgX, ggX, ogX, cstX); \
    float hvY = cellUpd(igY, fgY, ggY, ogY, cstY); \
    hnX[ibA] = f2h(hvX); \
    hnY[ibA] = f2h(hvY); \
    hvPX = (step == cidxXm1) ? hvX : hvPX; \
    hvCX = (step == cidxX)   ? hvX : hvCX; \
    hvPY = (step == cidxYm1) ? hvY : hvPY; \
    hvCY = (step == cidxY)   ? hvY : hvCY; \
    if (doXt && tc < 31) (xtG ? hnY : hnX)[xtDst] = f2h(rnnS[xtSrc + (tc + 1)*9]); \
    __syncthreads(); \
    ++tc; ++step; }

  int step = 0;
  for (int chunk = 0; chunk*32 <= maxIdx; ++chunk) {
    __syncthreads();                           // prior chunk / encoder reads of rnnS done
    *(float4*)&rnnS[pfR*292 + pfP*4] = pfA;    // commit prefetched chunk (rows 0-7)
    *(float4*)&rnnS[(pfR + 8)*292 + pfP*4] = pfB;  // rows 8-15
    if ((chunk + 1)*32 <= maxIdx) {            // issue next early
      pfA = rnnRowA[(chunk + 1)*72];
      pfB = rnnRowB[(chunk + 1)*72];
    }
    __syncthreads();
    if (doXt) hF[xtG][0][xtDst] = f2h(rnnS[xtSrc]);  // xt for first step (par==0)
    __syncthreads();
    const int lim = min(31, maxIdx - chunk*32);
    int tc = 0;
    while (tc + 1 <= lim) { STEP(0) STEP(1) }
    if (tc <= lim) { STEP(0) }                 // odd tail only on the last chunk
  }
#undef STEP
#undef MFMA16

  // flush snapshots (each lane owns distinct (unit,row) per group)
  snapP[cL][uA]     = hvPX;  snapC[cL][uA]     = hvCX;
  snapP[8 + cL][uA] = hvPY;  snapC[8 + cL][uA] = hvCY;
  if (t < NR) dS[t] = deltas[brS[t]*TT + idxS[t]];
  __syncthreads();

  // ---------------- decoder: 72 -> 288 -> 288 -> 8 (16 rows) ----------------
  for (int p = t; p < HH*16; p += NTH) {   // build dec_in into hS[u][r]
    int u = p >> 4, r = p & 15;
    float d = dS[r];
    float sp = snapP[r][u], sc = snapC[r][u];
    hS[u*16 + r] = fmaf(d, sc - sp, sp);
  }
  __syncthreads();

  // layer1: 288 x 72
  float* d1S = rnnS; // [n][16]
  {
    int n = t >> 1, rh = (t & 1)*8;
    float acc[8];
    float b = db1[n];
    #pragma unroll
    for (int j = 0; j < 8; ++j) acc[j] = b;
    const float4* w4 = (const float4*)(dW1 + n*HH);
    #pragma unroll 2
    for (int k4 = 0; k4 < 18; ++k4) {
      float4 w = w4[k4];
      FMA8(acc, w.x, &hS[(4*k4+0)*16 + rh]);
      FMA8(acc, w.y, &hS[(4*k4+1)*16 + rh]);
      FMA8(acc, w.z, &hS[(4*k4+2)*16 + rh]);
      FMA8(acc, w.w, &hS[(4*k4+3)*16 + rh]);
    }
    #pragma unroll
    for (int j = 0; j < 8; ++j) d1S[n*16 + rh + j] = ftanh(acc[j]);
  }
  __syncthreads();

  // layer2: 288 x 288
  float* d2S = gS;   // [n][16]
  {
    int n = t >> 1, rh = (t & 1)*8;
    float acc[8];
    float b = db2[n];
    #pragma unroll
    for (int j = 0; j < 8; ++j) acc[j] = b;
    const float4* w4 = (const float4*)(dW2 + n*288);
    #pragma unroll 2
    for (int k4 = 0; k4 < 72; ++k4) {
      float4 w = w4[k4];
      FMA8(acc, w.x, &d1S[(4*k4+0)*16 + rh]);
      FMA8(acc, w.y, &d1S[(4*k4+1)*16 + rh]);
      FMA8(acc, w.z, &d1S[(4*k4+2)*16 + rh]);
      FMA8(acc, w.w, &d1S[(4*k4+3)*16 + rh]);
    }
    #pragma unroll
    for (int j = 0; j < 8; ++j) d2S[n*16 + rh + j] = ftanh(acc[j]);
  }
  __syncthreads();

  // layer3: 8 x 288 (linear) + scatter store
  if (t < 128) {
    int o = t & 7, r = t >> 3;
    float acc3 = db3[o];
    const float* wr = dW3 + o*288;
    #pragma unroll 4
    for (int k = 0; k < 288; ++k) acc3 = fmaf(wr[k], d2S[k*16 + r], acc3);
    out[brS[r]*8 + o] = acc3;
  }
}

extern "C" void kernel_launch(void* const* d_in, const int* in_sizes, int n_in,
                              void* d_out, int out_size, void* d_ws, size_t ws_size,
                              hipStream_t stream) {
  const float* x      = (const float*)d_in[0];
  const float* rnn    = (const float*)d_in[1];
  const float* deltas = (const float*)d_in[2];
  const int*   h_lens = (const int*)  d_in[3];
  const float* W_ih   = (const float*)d_in[4];
  const float* W_hh   = (const float*)d_in[5];
  const float* b_ih   = (const float*)d_in[6];
  const float* b_hh   = (const float*)d_in[7];
  const float* eW1    = (const float*)d_in[8];
  const float* eb1    = (const float*)d_in[9];
  const float* eW2    = (const float*)d_in[10];
  const float* eb2    = (const float*)d_in[11];
  const float* eW3    = (const float*)d_in[12];
  const float* eb3    = (const float*)d_in[13];
  const float* dW1    = (const float*)d_in[14];
  const float* db1    = (const float*)d_in[15];
  const float* dW2    = (const float*)d_in[16];
  const float* db2    = (const float*)d_in[17];
  const float* dW3    = (const float*)d_in[18];
  const float* db3    = (const float*)d_in[19];
  float* out = (float*)d_out;

  int* perm = nullptr;
  if (ws_size >= 2048 * sizeof(int)) {
    perm = (int*)d_ws;
    cfm_sort<<<1, 256, 0, stream>>>(h_lens, perm);
  }
  cfm_main<<<NBLK, NTH, 0, stream>>>(x, rnn, deltas, h_lens, W_ih, W_hh, b_ih, b_hh,
                                     eW1, eb1, eW2, eb2, eW3, eb3,
                                     dW1, db1, dW2, db2, dW3, db3,
                                     perm, out);
}

// Round 3
// 445.147 us; speedup vs baseline: 1.1792x; 1.1792x over previous
//
#include <hip/hip_runtime.h>
#include <cstdint>

#define HH 72
#define NR 8
#define NTH 192        // 3 waves: each wave alone on a SIMD, 6 tiles/wave
#define NBLK 256
#define TT 512

typedef __attribute__((ext_vector_type(8))) _Float16 half8;
typedef __attribute__((ext_vector_type(4))) float f32x4;

#if __has_builtin(__builtin_amdgcn_exp2f)
#define EXP2(x) __builtin_amdgcn_exp2f(x)
#else
#define EXP2(x) exp2f(x)
#endif
#if __has_builtin(__builtin_amdgcn_rcpf)
#define RCP(x) __builtin_amdgcn_rcpf(x)
#else
#define RCP(x) (1.0f/(x))
#endif

__device__ __forceinline__ float fsig(float x) {
  float e = EXP2(x * -1.442695040888963f);
  return RCP(1.0f + e);
}
__device__ __forceinline__ float ftanh(float x) {
  float e = EXP2(x * -2.885390081777927f);
  return fmaf(2.0f, RCP(1.0f + e), -1.0f);
}

// fp32 -> fp16 bits (RNE via v_cvt_f16_f32)
__device__ __forceinline__ unsigned short f2h(float v) {
  union { _Float16 h; unsigned short u; } cv;
  cv.h = (_Float16)v;
  return cv.u;
}

// fragment ushort index for contraction-dim k, batch col m (0..7).
// Layout [kt*4+q][m=8][8]: 8 contiguous fp16 -> one ds_read_b128 per (group,m).
__device__ __forceinline__ int bidx(int k, int m) {
  return ((k >> 5)*4 + ((k >> 3) & 3))*64 + m*8 + (k & 7);
}

__device__ __forceinline__ float cellUpd(float ig, float fg, float gg, float og, float& c) {
  c = fmaf(fsig(fg), c, fsig(ig)*ftanh(gg));
  return fsig(og)*ftanh(c);
}

// accumulate 4 rows: A[r] += W_ * P_[r]
#define FMA4(A, W_, P_) { \
  const float4 _fa = *(const float4*)(P_); \
  A[0] = fmaf((W_), _fa.x, A[0]); A[1] = fmaf((W_), _fa.y, A[1]); \
  A[2] = fmaf((W_), _fa.z, A[2]); A[3] = fmaf((W_), _fa.w, A[3]); }

// counting sort of rows by h_lens (ascending) -> blocks get similar-length rows
__global__ void cfm_sort(const int* __restrict__ h_lens, int* __restrict__ perm) {
  __shared__ int hist[257];
  __shared__ int offs[257];
  const int t = threadIdx.x; // 256
  for (int i = t; i < 257; i += 256) hist[i] = 0;
  __syncthreads();
  for (int i = t; i < 2048; i += 256) {
    int bkt = min(max(h_lens[i] - 256, 0), 256);
    atomicAdd(&hist[bkt], 1);
  }
  __syncthreads();
  if (t == 0) { int s = 0; for (int i = 0; i < 257; ++i) { offs[i] = s; s += hist[i]; } }
  __syncthreads();
  for (int i = t; i < 2048; i += 256) {
    int bkt = min(max(h_lens[i] - 256, 0), 256);
    int pos = atomicAdd(&offs[bkt], 1);
    perm[pos] = i;
  }
}

// 3 waves/block, 8 rows/block, 6 MFMA tiles per wave, all weights in registers.
// Each wave runs alone on its SIMD (no issue-port sharing); the per-step barrier
// syncs only 3 waves running in parallel -> minimal convoy stagger.
__global__ __launch_bounds__(NTH, 1)
void cfm_main(const float* __restrict__ x, const float* __restrict__ rnn,
              const float* __restrict__ deltas, const int* __restrict__ h_lens,
              const float* __restrict__ W_ih, const float* __restrict__ W_hh,
              const float* __restrict__ b_ih, const float* __restrict__ b_hh,
              const float* __restrict__ eW1, const float* __restrict__ eb1,
              const float* __restrict__ eW2, const float* __restrict__ eb2,
              const float* __restrict__ eW3, const float* __restrict__ eb3,
              const float* __restrict__ dW1, const float* __restrict__ db1,
              const float* __restrict__ dW2, const float* __restrict__ db2,
              const float* __restrict__ dW3, const float* __restrict__ db3,
              const int* __restrict__ perm, float* __restrict__ out)
{
  __shared__ __align__(16) unsigned short hF[2][768];  // fp16 [h|xt|pad] B-fragments, dbuf
  __shared__ __align__(16) float gS[2304];             // enc z1S / dec d2S  [n][8]
  __shared__ __align__(16) float rnnS[2336];           // rnn chunk [8][292]; enc z2S / dec d1S
  __shared__ __align__(16) float snapP[NR][HH];
  __shared__ __align__(16) float snapC[NR][HH];
  __shared__ __align__(16) float hS[HH*NR];            // decoder dec_in [u][r]
  __shared__ __align__(16) float xS[8*NR];             // [k][r]
  __shared__ int brS[NR];
  __shared__ int idxS[NR];
  __shared__ float dS[NR];

  const int t  = threadIdx.x;
  const int bb = blockIdx.x;

  for (int i = t; i < 768; i += NTH) ((unsigned*)hF)[i] = 0;  // zero both buffers (pads!)

  if (t < NR) {
    int row = perm ? perm[bb*NR + t] : (bb*NR + t);
    brS[t]  = row;
    idxS[t] = h_lens[row] - 1;   // in [255, 511]
  }
  __syncthreads();

  int maxIdx = idxS[0];
  #pragma unroll
  for (int r = 1; r < NR; ++r) maxIdx = max(maxIdx, idxS[r]);

  const int lane = t & 63;
  const int wv   = t >> 6;                 // 0..2, tiles 6wv..6wv+5
  const int col  = lane & 15;
  const int q_a  = lane >> 4;
  const int cL   = col & 7;                // batch col (cols 8-15 are broadcast dups)
  const int gHi  = col >> 3;               // dup half: owns tiles 6wv+3gHi+{0,1,2}
  const int tb   = 6*wv + 3*gHi;
  const int uA0  = 4*(tb + 0) + q_a;       // 3 owned units
  const int uA1  = 4*(tb + 1) + q_a;
  const int uA2  = 4*(tb + 2) + q_a;
  const int ib0  = bidx(uA0, cL);
  const int ib1  = bidx(uA1, cL);
  const int ib2  = bidx(uA2, cL);
  const int cidxE  = idxS[cL];
  const int cidxm1 = cidxE - 1;
  const int bOff0 = (0*4 + q_a)*64 + cL*8; // broadcast read: col&7
  const int bOff1 = (1*4 + q_a)*64 + cL*8;
  const int bOff2 = (2*4 + q_a)*64 + cL*8;
  float cst0 = 0.f, cst1 = 0.f, cst2 = 0.f;
  float hP0 = 0.f, hP1 = 0.f, hP2 = 0.f;
  float hC0 = 0.f, hC1 = 0.f, hC2 = 0.f;

  // prefetch rnn chunk 0 into regs (3 float4/thread: 576 float4 = 8 rows * 288 floats)
  const int pfR = t / 24;                  // 0..7
  const int pfC = t - pfR*24;              // 0..23
  const float4* rnnRow = (const float4*)(rnn + (size_t)brS[pfR]*4608) + pfC*3;
  float4 pf0 = rnnRow[0];
  float4 pf1 = rnnRow[1];
  float4 pf2 = rnnRow[2];

  // xt staging lanes: 72 values/step (8 rows x 9 k)
  const bool doXt = (t < 72);
  int xtDst = 0, xtSrc = 0;
  if (doXt) {
    int rX = t / 9, kX = t - rX*9;
    xtDst = bidx(72 + kX, rX);
    xtSrc = rX*292 + kX;          // padded row stride 292 -> spreads banks
  }

  // ---------------- encoder: 8 -> 256 -> 256 -> 64 ----------------
  if (t < 64) { int r = t >> 3, k = t & 7; xS[k*8 + r] = x[brS[r]*8 + k]; }
  __syncthreads();

  float* z1S = gS;   // [n][8]
  for (int p = t; p < 512; p += NTH) {
    int n = p >> 1, rh = (p & 1)*4;
    float acc[4];
    float b = eb1[n];
    acc[0]=b; acc[1]=b; acc[2]=b; acc[3]=b;
    #pragma unroll
    for (int k = 0; k < 8; ++k) { float w = eW1[n*8 + k]; FMA4(acc, w, &xS[k*8 + rh]); }
    #pragma unroll
    for (int j = 0; j < 4; ++j) z1S[n*8 + rh + j] = ftanh(acc[j]);
  }
  __syncthreads();
  float* z2S = rnnS; // [n][8]
  for (int p = t; p < 512; p += NTH) {
    int n = p >> 1, rh = (p & 1)*4;
    float acc[4];
    float b = eb2[n];
    acc[0]=b; acc[1]=b; acc[2]=b; acc[3]=b;
    const float4* w4 = (const float4*)(eW2 + n*256);
    #pragma unroll 4
    for (int k4 = 0; k4 < 64; ++k4) {
      float4 w = w4[k4];
      FMA4(acc, w.x, &z1S[(4*k4+0)*8 + rh]);
      FMA4(acc, w.y, &z1S[(4*k4+1)*8 + rh]);
      FMA4(acc, w.z, &z1S[(4*k4+2)*8 + rh]);
      FMA4(acc, w.w, &z1S[(4*k4+3)*8 + rh]);
    }
    #pragma unroll
    for (int j = 0; j < 4; ++j) z2S[n*8 + rh + j] = ftanh(acc[j]);
  }
  __syncthreads();
  if (t < 128) {                       // h0 (linear) -> fragment k = 8+o, buffer 0
    int o = t >> 1, rh = (t & 1)*4;
    float acc[4];
    float b = eb3[o];
    acc[0]=b; acc[1]=b; acc[2]=b; acc[3]=b;
    const float4* w4 = (const float4*)(eW3 + o*256);
    #pragma unroll 4
    for (int k4 = 0; k4 < 64; ++k4) {
      float4 w = w4[k4];
      FMA4(acc, w.x, &z2S[(4*k4+0)*8 + rh]);
      FMA4(acc, w.y, &z2S[(4*k4+1)*8 + rh]);
      FMA4(acc, w.z, &z2S[(4*k4+2)*8 + rh]);
      FMA4(acc, w.w, &z2S[(4*k4+3)*8 + rh]);
    }
    #pragma unroll
    for (int j = 0; j < 4; ++j) hF[0][bidx(8 + o, rh + j)] = f2h(acc[j]);
  } else {                             // t in [128,192): x part -> k = 0..7, buffer 0
    int tt2 = t - 128; int r = tt2 >> 3, k = tt2 & 7;
    hF[0][bidx(k, r)] = f2h(xS[k*8 + r]);
  }

  // ---------------- weights as fp16 A-fragments (gate-permuted rows) ----------------
  // n' = 4*unit + gate ; src row = gate*72 + unit. A[row=n'][k], k = kt*32+q_a*8+j.
  half8 Af[6][3];
  f32x4 biasq[6];
  #pragma unroll
  for (int i = 0; i < 6; ++i) {
    int u = 4*(6*wv + i) + q_a;
    biasq[i].x = b_ih[u]       + b_hh[u];
    biasq[i].y = b_ih[72 + u]  + b_hh[72 + u];
    biasq[i].z = b_ih[144 + u] + b_hh[144 + u];
    biasq[i].w = b_ih[216 + u] + b_hh[216 + u];
    int nprime = (6*wv + i)*16 + col;
    int srcrow = (nprime & 3)*72 + (nprime >> 2);
    #pragma unroll
    for (int kt = 0; kt < 3; ++kt) {
      union { unsigned short u16[8]; half8 h; } cw;
      #pragma unroll
      for (int j = 0; j < 8; ++j) {
        int k = kt*32 + q_a*8 + j;
        float v = 0.f;
        if (k < 72)      v = W_hh[srcrow*HH + k];
        else if (k < 81) v = W_ih[srcrow*9 + (k - 72)];
        cw.u16[j] = f2h(v);
      }
      Af[i][kt] = cw.h;
    }
  }

  // ---------------- LSTM over time: one barrier per step (3 waves only) ----------
#define MFMA16(A, B, C) __builtin_amdgcn_mfma_f32_16x16x32_f16(A, B, C, 0, 0, 0)
#define STEP(PAR) { \
    const unsigned short* hb = &hF[PAR][0]; \
    unsigned short* hn = &hF[(PAR) ^ 1][0]; \
    half8 bf0 = *(const half8*)(hb + bOff0); \
    half8 bf1 = *(const half8*)(hb + bOff1); \
    half8 bf2 = *(const half8*)(hb + bOff2); \
    f32x4 a0 = MFMA16(Af[0][0], bf0, biasq[0]); \
    f32x4 a1 = MFMA16(Af[1][0], bf0, biasq[1]); \
    f32x4 a2 = MFMA16(Af[2][0], bf0, biasq[2]); \
    f32x4 a3 = MFMA16(Af[3][0], bf0, biasq[3]); \
    f32x4 a4 = MFMA16(Af[4][0], bf0, biasq[4]); \
    f32x4 a5 = MFMA16(Af[5][0], bf0, biasq[5]); \
    a0 = MFMA16(Af[0][1], bf1, a0);  a1 = MFMA16(Af[1][1], bf1, a1); \
    a2 = MFMA16(Af[2][1], bf1, a2);  a3 = MFMA16(Af[3][1], bf1, a3); \
    a4 = MFMA16(Af[4][1], bf1, a4);  a5 = MFMA16(Af[5][1], bf1, a5); \
    a0 = MFMA16(Af[0][2], bf2, a0);  a1 = MFMA16(Af[1][2], bf2, a1); \
    a2 = MFMA16(Af[2][2], bf2, a2);  a3 = MFMA16(Af[3][2], bf2, a3); \
    a4 = MFMA16(Af[4][2], bf2, a4);  a5 = MFMA16(Af[5][2], bf2, a5); \
    float i0 = gHi ? a3.x : a0.x, f0 = gHi ? a3.y : a0.y; \
    float g0 = gHi ? a3.z : a0.z, o0 = gHi ? a3.w : a0.w; \
    float i1 = gHi ? a4.x : a1.x, f1 = gHi ? a4.y : a1.y; \
    float g1 = gHi ? a4.z : a1.z, o1 = gHi ? a4.w : a1.w; \
    float i2 = gHi ? a5.x : a2.x, f2 = gHi ? a5.y : a2.y; \
    float g2 = gHi ? a5.z : a2.z, o2 = gHi ? a5.w : a2.w; \
    float hv0 = cellUpd(i0, f0, g0, o0, cst0); \
    float hv1 = cellUpd(i1, f1, g1, o1, cst1); \
    float hv2 = cellUpd(i2, f2, g2, o2, cst2); \
    hn[ib0] = f2h(hv0); \
    hn[ib1] = f2h(hv1); \
    hn[ib2] = f2h(hv2); \
    hP0 = (step == cidxm1) ? hv0 : hP0;  hC0 = (step == cidxE) ? hv0 : hC0; \
    hP1 = (step == cidxm1) ? hv1 : hP1;  hC1 = (step == cidxE) ? hv1 : hC1; \
    hP2 = (step == cidxm1) ? hv2 : hP2;  hC2 = (step == cidxE) ? hv2 : hC2; \
    if (doXt && tc < 31) hn[xtDst] = f2h(rnnS[xtSrc + (tc + 1)*9]); \
    __syncthreads(); \
    ++tc; ++step; }

  int step = 0;
  for (int chunk = 0; chunk*32 <= maxIdx; ++chunk) {
    __syncthreads();                            // prior chunk / encoder reads of rnnS done
    *(float4*)&rnnS[pfR*292 + pfC*12 + 0] = pf0;  // commit prefetched chunk
    *(float4*)&rnnS[pfR*292 + pfC*12 + 4] = pf1;
    *(float4*)&rnnS[pfR*292 + pfC*12 + 8] = pf2;
    if ((chunk + 1)*32 <= maxIdx) {             // issue next early
      pf0 = rnnRow[(chunk + 1)*72 + 0];
      pf1 = rnnRow[(chunk + 1)*72 + 1];
      pf2 = rnnRow[(chunk + 1)*72 + 2];
    }
    __syncthreads();
    if (doXt) hF[0][xtDst] = f2h(rnnS[xtSrc]);  // xt for first step of chunk (par==0)
    __syncthreads();
    const int lim = min(31, maxIdx - chunk*32);
    int tc = 0;
    while (tc + 1 <= lim) { STEP(0) STEP(1) }
    if (tc <= lim) { STEP(0) }                  // odd tail only on the last chunk
  }
#undef STEP
#undef MFMA16

  // flush snapshots (each lane owns 3 distinct (unit,row) cells)
  snapP[cL][uA0] = hP0;  snapC[cL][uA0] = hC0;
  snapP[cL][uA1] = hP1;  snapC[cL][uA1] = hC1;
  snapP[cL][uA2] = hP2;  snapC[cL][uA2] = hC2;
  if (t < NR) dS[t] = deltas[brS[t]*TT + idxS[t]];
  __syncthreads();

  // ---------------- decoder: 72 -> 288 -> 288 -> 8 ----------------
  for (int p = t; p < HH*NR; p += NTH) {   // build dec_in into hS[u][r]
    int u = p >> 3, r = p & 7;
    float d = dS[r];
    float sp = snapP[r][u], sc = snapC[r][u];
    hS[u*8 + r] = fmaf(d, sc - sp, sp);
  }
  __syncthreads();

  // layer1: 288 x 72
  float* d1S = rnnS; // [n][8]
  for (int p = t; p < 576; p += NTH) {
    int n = p >> 1, rh = (p & 1)*4;
    float acc[4];
    float b = db1[n];
    acc[0]=b; acc[1]=b; acc[2]=b; acc[3]=b;
    const float4* w4 = (const float4*)(dW1 + n*HH);
    #pragma unroll 2
    for (int k4 = 0; k4 < 18; ++k4) {
      float4 w = w4[k4];
      FMA4(acc, w.x, &hS[(4*k4+0)*8 + rh]);
      FMA4(acc, w.y, &hS[(4*k4+1)*8 + rh]);
      FMA4(acc, w.z, &hS[(4*k4+2)*8 + rh]);
      FMA4(acc, w.w, &hS[(4*k4+3)*8 + rh]);
    }
    #pragma unroll
    for (int j = 0; j < 4; ++j) d1S[n*8 + rh + j] = ftanh(acc[j]);
  }
  __syncthreads();

  // layer2: 288 x 288
  float* d2S = gS;   // [n][8]
  for (int p = t; p < 576; p += NTH) {
    int n = p >> 1, rh = (p & 1)*4;
    float acc[4];
    float b = db2[n];
    acc[0]=b; acc[1]=b; acc[2]=b; acc[3]=b;
    const float4* w4 = (const float4*)(dW2 + n*288);
    #pragma unroll 4
    for (int k4 = 0; k4 < 72; ++k4) {
      float4 w = w4[k4];
      FMA4(acc, w.x, &d1S[(4*k4+0)*8 + rh]);
      FMA4(acc, w.y, &d1S[(4*k4+1)*8 + rh]);
      FMA4(acc, w.z, &d1S[(4*k4+2)*8 + rh]);
      FMA4(acc, w.w, &d1S[(4*k4+3)*8 + rh]);
    }
    #pragma unroll
    for (int j = 0; j < 4; ++j) d2S[n*8 + rh + j] = ftanh(acc[j]);
  }
  __syncthreads();

  // layer3: 8 x 288 (linear) + scatter store
  if (t < 64) {
    int o = t & 7, r = t >> 3;
    float acc3 = db3[o];
    const float* wr = dW3 + o*288;
    #pragma unroll 4
    for (int k = 0; k < 288; ++k) acc3 = fmaf(wr[k], d2S[k*8 + r], acc3);
    out[brS[r]*8 + o] = acc3;
  }
}

extern "C" void kernel_launch(void* const* d_in, const int* in_sizes, int n_in,
                              void* d_out, int out_size, void* d_ws, size_t ws_size,
                              hipStream_t stream) {
  const float* x      = (const float*)d_in[0];
  const float* rnn    = (const float*)d_in[1];
  const float* deltas = (const float*)d_in[2];
  const int*   h_lens = (const int*)  d_in[3];
  const float* W_ih   = (const float*)d_in[4];
  const float* W_hh   = (const float*)d_in[5];
  const float* b_ih   = (const float*)d_in[6];
  const float* b_hh   = (const float*)d_in[7];
  const float* eW1    = (const float*)d_in[8];
  const float* eb1    = (const float*)d_in[9];
  const float* eW2    = (const float*)d_in[10];
  const float* eb2    = (const float*)d_in[11];
  const float* eW3    = (const float*)d_in[12];
  const float* eb3    = (const float*)d_in[13];
  const float* dW1    = (const float*)d_in[14];
  const float* db1    = (const float*)d_in[15];
  const float* dW2    = (const float*)d_in[16];
  const float* db2    = (const float*)d_in[17];
  const float* dW3    = (const float*)d_in[18];
  const float* db3    = (const float*)d_in[19];
  float* out = (float*)d_out;

  int* perm = nullptr;
  if (ws_size >= 2048 * sizeof(int)) {
    perm = (int*)d_ws;
    cfm_sort<<<1, 256, 0, stream>>>(h_lens, perm);
  }
  cfm_main<<<NBLK, NTH, 0, stream>>>(x, rnn, deltas, h_lens, W_ih, W_hh, b_ih, b_hh,
                                     eW1, eb1, eW2, eb2, eW3, eb3,
                                     dW1, db1, dW2, db2, dW3, db3,
                                     perm, out);
}